// Round 5
// baseline (200.945 us; speedup 1.0000x reference)
//
#include <hip/hip_runtime.h>

#define BDIM 256

constexpr int Vv = 3, Cc = 64, Hh = 96, Ww = 96, Dd = 48;
constexpr int HW = Hh * Ww;          // 9216
constexpr int NPIX = Dd * HW;        // 442368
constexpr int DHW = Dd * HW;         // output channel stride

// ---------------------------------------------------------------------------
// Single-view warp computation (verified numerics: same fp contract(off)
// region and operation order as all passing rounds).
// ---------------------------------------------------------------------------
__device__ __forceinline__ void compute_warp_v(const float* __restrict__ P, float depth,
                                               float xf, float yf,
                                               int offs[4], float wts[4], float& inbf)
{
#pragma clang fp contract(off)
    const float r00 = P[0], r01 = P[1], r02 = P[2],  t0 = P[3];
    const float r10 = P[4], r11 = P[5], r12 = P[6],  t1 = P[7];
    const float r20 = P[8], r21 = P[9], r22 = P[10], t2 = P[11];

    const float px = ((r00 * xf + r01 * yf) + r02) + t0 / depth;
    const float py = ((r10 * xf + r11 * yf) + r12) + t1 / depth;
    const float pz = ((r20 * xf + r21 * yf) + r22) + t2 / depth;

    const float xy0 = px / pz;
    const float xy1 = py / pz;
    const float gx = xy0 / ((float)(Ww - 1) * 0.5f) - 1.0f;
    const float gy = xy1 / ((float)(Hh - 1) * 0.5f) - 1.0f;

    const bool inb = (gx > -1.0f) && (gx < 1.0f) && (gy > -1.0f) && (gy < 1.0f);
    inbf = inb ? 1.0f : 0.0f;

    const float sx = (gx + 1.0f) * 0.5f * (float)(Ww - 1);
    const float sy = (gy + 1.0f) * 0.5f * (float)(Hh - 1);
    const float x0 = floorf(sx), y0 = floorf(sy);
    const float wx1 = sx - x0, wy1 = sy - y0;
    const float wx0 = 1.0f - wx1, wy0 = 1.0f - wy1;

#pragma unroll
    for (int k = 0; k < 4; ++k) {
        const float xi = (k & 1) ? (x0 + 1.0f) : x0;
        const float yi = (k & 2) ? (y0 + 1.0f) : y0;
        const float wk = ((k & 1) ? wx1 : wx0) * ((k & 2) ? wy1 : wy0);
        const bool valid = (xi >= 0.0f) && (xi <= (float)(Ww - 1)) &&
                           (yi >= 0.0f) && (yi <= (float)(Hh - 1));
        const float xc = fminf(fmaxf(xi, 0.0f), (float)(Ww - 1));
        const float yc = fminf(fmaxf(yi, 0.0f), (float)(Hh - 1));
        offs[k] = (int)yc * Ww + (int)xc;
        wts[k] = valid ? wk : 0.0f;
    }
}

// 2-view wrapper for the fallback kernel.
__device__ __forceinline__ void compute_warp(const float* __restrict__ proj, float depth,
                                             float xf, float yf,
                                             int offs[2][4], float wts[2][4], float& msum)
{
    msum = 1.0f;
#pragma unroll
    for (int v = 0; v < 2; ++v) {
        float inb;
        compute_warp_v(proj + (v + 1) * 12, depth, xf, yf, offs[v], wts[v], inb);
        msum += inb;
    }
}

__device__ __forceinline__ float var_one(float fr, float a1, float a2, float cnt)
{
    const float s  = fr + a1 + a2;
    const float q  = fr * fr + a1 * a1 + a2 * a2;
    const float sc = s * cnt;
    return q * cnt - sc * sc;
}

// ---------------------------------------------------------------------------
// feats (V, C, HW) -> ftr (V, HW, C)   (channel-minor for coalesced reads)
// ---------------------------------------------------------------------------
__global__ void __launch_bounds__(BDIM) transpose_feats_kernel(const float* __restrict__ feats,
                                                               float* __restrict__ ft)
{
    __shared__ float tile[64][65];
    const int v  = blockIdx.y;
    const int p0 = blockIdx.x * 64;
    const float* src = feats + (size_t)v * Cc * HW;

    const int px = threadIdx.x & 63;
    const int c0 = threadIdx.x >> 6;
#pragma unroll
    for (int c = c0; c < Cc; c += 4)
        tile[c][px] = src[(size_t)c * HW + p0 + px];
    __syncthreads();

    const int cc  = threadIdx.x & 63;
    const int pr0 = threadIdx.x >> 6;
    float* dst = ft + ((size_t)v * HW + p0) * Cc;
#pragma unroll
    for (int p = pr0; p < 64; p += 4)
        dst[p * Cc + cc] = tile[cc][p];
}

// ---------------------------------------------------------------------------
// main kernel: one block per (h, depth-pair). Round-5 structure: occupancy-
// focused. LDS 26.2 KB (single-depth s_tile slab, 4 store sub-phases) and
// sequential-depth gathers (9 live float4 instead of 17) with
// __launch_bounds__(256,5) -> 5 waves/SIMD (20 waves/CU, up from 16).
// Cross-depth L1 line reuse is preserved: dd=1's sub-phase re-touches the
// same ~10KB/iter line set immediately after dd=0 (fits 32KB L1).
// Store path: coalesced full-line stores from s_tile (verified; direct
// stores cost +40us in R3 from partial-line RMW).
// ---------------------------------------------------------------------------
__global__ void __launch_bounds__(BDIM, 5) ge_row_kernel(
    const float* __restrict__ imgs, const float* __restrict__ ftr,
    const float* __restrict__ proj, const float* __restrict__ depthv,
    float* __restrict__ out)
{
    __shared__ float s_tile[Cc / 2][Ww + 1];            // 32 x 97 = 12.4 KB
    __shared__ alignas(16) int   s_base[2][2][Ww][4];   // [view][dd][pixel][corner]
    __shared__ alignas(16) float s_wt[2][2][Ww][4];
    __shared__ float s_inb[2][2][Ww];

    const int blk = blockIdx.x;              // h * (Dd/2) + dq
    const int h   = blk / (Dd / 2);
    const int dq  = blk - h * (Dd / 2);
    const int d0  = dq * 2;
    const int tid = threadIdx.x;
    const int rowb0 = d0 * HW + h * Ww;      // output offset of (d0,h,0)

    // ---- Phase 1: 384 (view,depth,pixel) tasks striped over 256 threads ----
    for (int t = tid; t < 2 * 2 * Ww; t += BDIM) {
        const int v  = t / (2 * Ww);
        const int r  = t - v * (2 * Ww);
        const int dd = r / Ww;
        const int w  = r - dd * Ww;

        int offs[4];
        float wts[4];
        float inb;
        compute_warp_v(proj + (v + 1) * 12, depthv[d0 + dd], (float)w, (float)h,
                       offs, wts, inb);
        s_inb[v][dd][w] = inb;
#pragma unroll
        for (int k = 0; k < 4; ++k) {
            s_base[v][dd][w][k] = ((v + 1) * HW + offs[k]) * Cc;
            s_wt[v][dd][w][k]   = wts[k];
        }

        // warped image channels for this view/depth
        const float* ib = imgs + (size_t)(v + 1) * 3 * HW;
#pragma unroll
        for (int c = 0; c < 3; ++c) {
            const float* p = ib + (size_t)c * HW;
            const float acc = wts[0] * p[offs[0]] + wts[1] * p[offs[1]] +
                              wts[2] * p[offs[2]] + wts[3] * p[offs[3]];
            out[(3 * (v + 1) + c) * DHW + rowb0 + dd * HW + w] = acc;
        }
    }
    if (tid < Ww) {
        const int hw = h * Ww + tid;
#pragma unroll
        for (int c = 0; c < 3; ++c) {
            const float val = imgs[c * HW + hw];
            out[c * DHW + rowb0 + tid]      = val;   // depth d0
            out[c * DHW + rowb0 + HW + tid] = val;   // depth d0+1
        }
    }
    __syncthreads();

    // ---- Phase 2/3: 4 sub-phases (channel-half x depth) ----
    const int wave = tid >> 6;
    const int lane = tid & 63;
    const int sub  = lane >> 3;          // pixel-within-octet 0..7
    const int cq   = lane & 7;           // channel quad within half
    const int c4   = cq << 2;            // 0,4,...,28
    const int p0   = wave * (Ww / 4);    // 24 pixels per wave

#pragma unroll
    for (int hc = 0; hc < 2; ++hc) {
        const int ch0 = hc * (Cc / 2);
        const float* fb = ftr + ch0 + c4;

#pragma unroll
        for (int dd = 0; dd < 2; ++dd) {
#pragma unroll
            for (int i = 0; i < 3; ++i) {    // 3 iterations x 8 pixels
                const int p = p0 + i * 8 + sub;
                const float cnt = 1.0f / (1.0f + s_inb[0][dd][p] + s_inb[1][dd][p]);
                const int4   b0 = *reinterpret_cast<const int4*>(&s_base[0][dd][p][0]);
                const int4   b1 = *reinterpret_cast<const int4*>(&s_base[1][dd][p][0]);
                const float4 w0 = *reinterpret_cast<const float4*>(&s_wt[0][dd][p][0]);
                const float4 w1 = *reinterpret_cast<const float4*>(&s_wt[1][dd][p][0]);

                const float4 fr  = *reinterpret_cast<const float4*>(fb + (size_t)(h * Ww + p) * Cc);
                const float4 v00 = *reinterpret_cast<const float4*>(fb + b0.x);
                const float4 v01 = *reinterpret_cast<const float4*>(fb + b0.y);
                const float4 v02 = *reinterpret_cast<const float4*>(fb + b0.z);
                const float4 v03 = *reinterpret_cast<const float4*>(fb + b0.w);
                const float4 v10 = *reinterpret_cast<const float4*>(fb + b1.x);
                const float4 v11 = *reinterpret_cast<const float4*>(fb + b1.y);
                const float4 v12 = *reinterpret_cast<const float4*>(fb + b1.z);
                const float4 v13 = *reinterpret_cast<const float4*>(fb + b1.w);

                {
                    const float a1 = w0.x * v00.x + w0.y * v01.x + w0.z * v02.x + w0.w * v03.x;
                    const float a2 = w1.x * v10.x + w1.y * v11.x + w1.z * v12.x + w1.w * v13.x;
                    s_tile[c4 + 0][p] = var_one(fr.x, a1, a2, cnt);
                }
                {
                    const float a1 = w0.x * v00.y + w0.y * v01.y + w0.z * v02.y + w0.w * v03.y;
                    const float a2 = w1.x * v10.y + w1.y * v11.y + w1.z * v12.y + w1.w * v13.y;
                    s_tile[c4 + 1][p] = var_one(fr.y, a1, a2, cnt);
                }
                {
                    const float a1 = w0.x * v00.z + w0.y * v01.z + w0.z * v02.z + w0.w * v03.z;
                    const float a2 = w1.x * v10.z + w1.y * v11.z + w1.z * v12.z + w1.w * v13.z;
                    s_tile[c4 + 2][p] = var_one(fr.z, a1, a2, cnt);
                }
                {
                    const float a1 = w0.x * v00.w + w0.y * v01.w + w0.z * v02.w + w0.w * v03.w;
                    const float a2 = w1.x * v10.w + w1.y * v11.w + w1.z * v12.w + w1.w * v13.w;
                    s_tile[c4 + 3][p] = var_one(fr.w, a1, a2, cnt);
                }
            }
            __syncthreads();

            // coalesced full-line stores: 32 channels x 96 pixels for this depth
#pragma unroll
            for (int j = 0; j < ((Cc / 2) * Ww) / BDIM; ++j) {   // 12 iterations
                const int idx = tid + j * BDIM;
                const int cc  = idx / Ww;
                const int p   = idx - cc * Ww;
                out[(9 + ch0 + cc) * DHW + rowb0 + dd * HW + p] = s_tile[cc][p];
            }
            __syncthreads();
        }
    }
}

// ---------------------------------------------------------------------------
// fallback (no workspace needed) — only used if ws_size is too small
// ---------------------------------------------------------------------------
__global__ void __launch_bounds__(BDIM) ge_direct_kernel(
    const float* __restrict__ imgs, const float* __restrict__ feats,
    const float* __restrict__ proj, const float* __restrict__ depthv,
    float* __restrict__ out)
{
    const int idx = blockIdx.x * BDIM + threadIdx.x;
    if (idx >= NPIX) return;
    const int w = idx % Ww;
    const int t = idx / Ww;
    const int h = t % Hh;
    const int d = t / Hh;
    const int ohw = h * Ww + w;

    int offs[2][4];
    float wts[2][4];
    float msum;
    compute_warp(proj, depthv[d], (float)w, (float)h, offs, wts, msum);

    const int obase = d * HW + ohw;
#pragma unroll
    for (int c = 0; c < 3; ++c)
        out[c * DHW + obase] = imgs[c * HW + ohw];

#pragma unroll
    for (int v = 0; v < 2; ++v) {
        const float* ib = imgs + (size_t)(v + 1) * 3 * HW;
#pragma unroll
        for (int c = 0; c < 3; ++c) {
            const float* p = ib + (size_t)c * HW;
            const float acc = wts[v][0] * p[offs[v][0]] + wts[v][1] * p[offs[v][1]] +
                              wts[v][2] * p[offs[v][2]] + wts[v][3] * p[offs[v][3]];
            out[(3 * (v + 1) + c) * DHW + obase] = acc;
        }
    }

    const float count = 1.0f / msum;
    const float* f0 = feats;
    const float* f1 = feats + (size_t)Cc * HW;
    const float* f2 = feats + (size_t)2 * Cc * HW;
#pragma unroll 8
    for (int c = 0; c < Cc; ++c) {
        const float fr = f0[(size_t)c * HW + ohw];
        const float* p1 = f1 + (size_t)c * HW;
        const float* p2 = f2 + (size_t)c * HW;
        const float a1 = wts[0][0] * p1[offs[0][0]] + wts[0][1] * p1[offs[0][1]] +
                         wts[0][2] * p1[offs[0][2]] + wts[0][3] * p1[offs[0][3]];
        const float a2 = wts[1][0] * p2[offs[1][0]] + wts[1][1] * p2[offs[1][1]] +
                         wts[1][2] * p2[offs[1][2]] + wts[1][3] * p2[offs[1][3]];
        const float s = fr + a1 + a2;
        const float sq = fr * fr + a1 * a1 + a2 * a2;
        const float sc = s * count;
        out[(3 * Vv + c) * DHW + obase] = sq * count - sc * sc;
    }
}

extern "C" void kernel_launch(void* const* d_in, const int* in_sizes, int n_in,
                              void* d_out, int out_size, void* d_ws, size_t ws_size,
                              hipStream_t stream)
{
    const float* imgs   = (const float*)d_in[0];
    const float* feats  = (const float*)d_in[1];
    const float* proj   = (const float*)d_in[2];
    const float* depthv = (const float*)d_in[3];
    float* out = (float*)d_out;

    const size_t need = (size_t)Vv * HW * Cc * sizeof(float);   // 7.08 MB

    if (ws_size >= need) {
        float* ftr = (float*)d_ws;
        dim3 g1(HW / 64, Vv);
        transpose_feats_kernel<<<g1, BDIM, 0, stream>>>(feats, ftr);
        ge_row_kernel<<<Hh * (Dd / 2), BDIM, 0, stream>>>(imgs, ftr, proj, depthv, out);
    } else {
        const int blocks = (NPIX + BDIM - 1) / BDIM;
        ge_direct_kernel<<<blocks, BDIM, 0, stream>>>(imgs, feats, proj, depthv, out);
    }
}

// Round 6
// 170.086 us; speedup vs baseline: 1.1814x; 1.1814x over previous
//
#include <hip/hip_runtime.h>

#define BDIM 256

constexpr int Vv = 3, Cc = 64, Hh = 96, Ww = 96, Dd = 48;
constexpr int HW = Hh * Ww;          // 9216
constexpr int NPIX = Dd * HW;        // 442368
constexpr int DHW = Dd * HW;         // output channel stride
constexpr int NXCD = 8;
constexpr int WP = Ww + 4;           // 100: 16B-aligned s_tile rows for float4 stores

// ---------------------------------------------------------------------------
// Single-view warp computation (verified numerics: same fp contract(off)
// region and operation order as all passing rounds).
// ---------------------------------------------------------------------------
__device__ __forceinline__ void compute_warp_v(const float* __restrict__ P, float depth,
                                               float xf, float yf,
                                               int offs[4], float wts[4], float& inbf)
{
#pragma clang fp contract(off)
    const float r00 = P[0], r01 = P[1], r02 = P[2],  t0 = P[3];
    const float r10 = P[4], r11 = P[5], r12 = P[6],  t1 = P[7];
    const float r20 = P[8], r21 = P[9], r22 = P[10], t2 = P[11];

    const float px = ((r00 * xf + r01 * yf) + r02) + t0 / depth;
    const float py = ((r10 * xf + r11 * yf) + r12) + t1 / depth;
    const float pz = ((r20 * xf + r21 * yf) + r22) + t2 / depth;

    const float xy0 = px / pz;
    const float xy1 = py / pz;
    const float gx = xy0 / ((float)(Ww - 1) * 0.5f) - 1.0f;
    const float gy = xy1 / ((float)(Hh - 1) * 0.5f) - 1.0f;

    const bool inb = (gx > -1.0f) && (gx < 1.0f) && (gy > -1.0f) && (gy < 1.0f);
    inbf = inb ? 1.0f : 0.0f;

    const float sx = (gx + 1.0f) * 0.5f * (float)(Ww - 1);
    const float sy = (gy + 1.0f) * 0.5f * (float)(Hh - 1);
    const float x0 = floorf(sx), y0 = floorf(sy);
    const float wx1 = sx - x0, wy1 = sy - y0;
    const float wx0 = 1.0f - wx1, wy0 = 1.0f - wy1;

#pragma unroll
    for (int k = 0; k < 4; ++k) {
        const float xi = (k & 1) ? (x0 + 1.0f) : x0;
        const float yi = (k & 2) ? (y0 + 1.0f) : y0;
        const float wk = ((k & 1) ? wx1 : wx0) * ((k & 2) ? wy1 : wy0);
        const bool valid = (xi >= 0.0f) && (xi <= (float)(Ww - 1)) &&
                           (yi >= 0.0f) && (yi <= (float)(Hh - 1));
        const float xc = fminf(fmaxf(xi, 0.0f), (float)(Ww - 1));
        const float yc = fminf(fmaxf(yi, 0.0f), (float)(Hh - 1));
        offs[k] = (int)yc * Ww + (int)xc;
        wts[k] = valid ? wk : 0.0f;
    }
}

// 2-view wrapper for the fallback kernel.
__device__ __forceinline__ void compute_warp(const float* __restrict__ proj, float depth,
                                             float xf, float yf,
                                             int offs[2][4], float wts[2][4], float& msum)
{
    msum = 1.0f;
#pragma unroll
    for (int v = 0; v < 2; ++v) {
        float inb;
        compute_warp_v(proj + (v + 1) * 12, depth, xf, yf, offs[v], wts[v], inb);
        msum += inb;
    }
}

__device__ __forceinline__ float var_one(float fr, float a1, float a2, float cnt)
{
    const float s  = fr + a1 + a2;
    const float q  = fr * fr + a1 * a1 + a2 * a2;
    const float sc = s * cnt;
    return q * cnt - sc * sc;
}

// ---------------------------------------------------------------------------
// feats (V, C, HW) -> ftr (V, HW, C)   (channel-minor for coalesced reads)
// ---------------------------------------------------------------------------
__global__ void __launch_bounds__(BDIM) transpose_feats_kernel(const float* __restrict__ feats,
                                                               float* __restrict__ ft)
{
    __shared__ float tile[64][65];
    const int v  = blockIdx.y;
    const int p0 = blockIdx.x * 64;
    const float* src = feats + (size_t)v * Cc * HW;

    const int px = threadIdx.x & 63;
    const int c0 = threadIdx.x >> 6;
#pragma unroll
    for (int c = c0; c < Cc; c += 4)
        tile[c][px] = src[(size_t)c * HW + p0 + px];
    __syncthreads();

    const int cc  = threadIdx.x & 63;
    const int pr0 = threadIdx.x >> 6;
    float* dst = ft + ((size_t)v * HW + p0) * Cc;
#pragma unroll
    for (int p = pr0; p < 64; p += 4)
        dst[p * Cc + cc] = tile[cc][p];
}

// ---------------------------------------------------------------------------
// main kernel: one block per (h, depth-pair) — R4 structure (measured best):
// both depths gathered in the SAME iteration (d1's corner lines ~70% L1 hits,
// depth-invariant fr loaded once), s_tile + coalesced full-line stores.
// R6 additions: (a) bijective XCD-chunked block mapping — each XCD owns 288
// consecutive blocks = 12 h-rows x all 24 depth-pairs, keeping an h-row's
// heavily-shared corner lines in ONE XCD's L2 (R5 measured FETCH 46MB when
// depth-neighbors were scattered round-robin; R3-style chunking showed 2MB).
// (b) float4 Phase-3 stores via 16B-aligned s_tile rows (WP=100): 6 vector
// store iterations instead of 24 scalar.
// ---------------------------------------------------------------------------
__global__ void __launch_bounds__(BDIM) ge_row_kernel(
    const float* __restrict__ imgs, const float* __restrict__ ftr,
    const float* __restrict__ proj, const float* __restrict__ depthv,
    float* __restrict__ out)
{
    __shared__ alignas(16) float s_tile[2][Cc / 2][WP]; // 2 depths x 32ch x 100, 25 KB
    __shared__ alignas(16) int   s_base[2][2][Ww][4];   // [view][dd][pixel][corner]
    __shared__ alignas(16) float s_wt[2][2][Ww][4];
    __shared__ float s_inb[2][2][Ww];

    // XCD-chunked bijective swizzle: phys blockIdx round-robins XCDs (%8);
    // logical blk ordered (h-major, depth-pair-minor). 2304 % 8 == 0.
    const int nper = (Hh * (Dd / 2)) / NXCD;            // 288
    const int blk  = (blockIdx.x & (NXCD - 1)) * nper + (blockIdx.x >> 3);
    const int h   = blk / (Dd / 2);
    const int dq  = blk - h * (Dd / 2);
    const int d0  = dq * 2;
    const int tid = threadIdx.x;
    const int rowb0 = d0 * HW + h * Ww;      // output offset of (d0,h,0)

    // ---- Phase 1: 192 threads, one (view,pixel) each, both depths ----
    if (tid < 2 * Ww) {
        const int v = (tid >= Ww) ? 1 : 0;
        const int w = tid - v * Ww;
        const float* ib = imgs + (size_t)(v + 1) * 3 * HW;
#pragma unroll
        for (int dd = 0; dd < 2; ++dd) {
            int offs[4];
            float wts[4];
            float inb;
            compute_warp_v(proj + (v + 1) * 12, depthv[d0 + dd], (float)w, (float)h,
                           offs, wts, inb);
            s_inb[v][dd][w] = inb;
#pragma unroll
            for (int k = 0; k < 4; ++k) {
                s_base[v][dd][w][k] = ((v + 1) * HW + offs[k]) * Cc;
                s_wt[v][dd][w][k]   = wts[k];
            }
            // warped image channels for this view/depth
#pragma unroll
            for (int c = 0; c < 3; ++c) {
                const float* p = ib + (size_t)c * HW;
                const float acc = wts[0] * p[offs[0]] + wts[1] * p[offs[1]] +
                                  wts[2] * p[offs[2]] + wts[3] * p[offs[3]];
                out[(3 * (v + 1) + c) * DHW + rowb0 + dd * HW + w] = acc;
            }
        }
    }
    if (tid < Ww) {
        const int hw = h * Ww + tid;
#pragma unroll
        for (int c = 0; c < 3; ++c) {
            const float val = imgs[c * HW + hw];
            out[c * DHW + rowb0 + tid]      = val;   // depth d0
            out[c * DHW + rowb0 + HW + tid] = val;   // depth d0+1
        }
    }
    __syncthreads();

    // ---- Phase 2/3: two channel-halves, both depths interleaved ----
    const int wave = tid >> 6;
    const int lane = tid & 63;
    const int sub  = lane >> 3;          // pixel-within-octet 0..7
    const int cq   = lane & 7;           // channel quad within half
    const int c4   = cq << 2;            // 0,4,...,28
    const int p0   = wave * (Ww / 4);    // 24 pixels per wave

#pragma unroll
    for (int hc = 0; hc < 2; ++hc) {
        const int ch0 = hc * (Cc / 2);

        for (int i = 0; i < 3; ++i) {    // 3 iterations x 8 pixels
            const int p = p0 + i * 8 + sub;
            const int4   b00 = *reinterpret_cast<const int4*>(&s_base[0][0][p][0]);
            const int4   b10 = *reinterpret_cast<const int4*>(&s_base[1][0][p][0]);
            const int4   b01 = *reinterpret_cast<const int4*>(&s_base[0][1][p][0]);
            const int4   b11 = *reinterpret_cast<const int4*>(&s_base[1][1][p][0]);
            const float4 w00 = *reinterpret_cast<const float4*>(&s_wt[0][0][p][0]);
            const float4 w10 = *reinterpret_cast<const float4*>(&s_wt[1][0][p][0]);
            const float4 w01 = *reinterpret_cast<const float4*>(&s_wt[0][1][p][0]);
            const float4 w11 = *reinterpret_cast<const float4*>(&s_wt[1][1][p][0]);
            const float cnt0 = 1.0f / (1.0f + s_inb[0][0][p] + s_inb[1][0][p]);
            const float cnt1 = 1.0f / (1.0f + s_inb[0][1][p] + s_inb[1][1][p]);

            // depth-invariant ref feature: loaded once, reused for both depths
            const float4 fr = *reinterpret_cast<const float4*>(
                ftr + (size_t)(h * Ww + p) * Cc + ch0 + c4);

            // depth d0 corners
            const float4 a00 = *reinterpret_cast<const float4*>(ftr + b00.x + ch0 + c4);
            const float4 a01 = *reinterpret_cast<const float4*>(ftr + b00.y + ch0 + c4);
            const float4 a02 = *reinterpret_cast<const float4*>(ftr + b00.z + ch0 + c4);
            const float4 a03 = *reinterpret_cast<const float4*>(ftr + b00.w + ch0 + c4);
            const float4 a10 = *reinterpret_cast<const float4*>(ftr + b10.x + ch0 + c4);
            const float4 a11 = *reinterpret_cast<const float4*>(ftr + b10.y + ch0 + c4);
            const float4 a12 = *reinterpret_cast<const float4*>(ftr + b10.z + ch0 + c4);
            const float4 a13 = *reinterpret_cast<const float4*>(ftr + b10.w + ch0 + c4);
            // depth d0+1 corners (mostly the same 128B lines -> L1 hits)
            const float4 c00 = *reinterpret_cast<const float4*>(ftr + b01.x + ch0 + c4);
            const float4 c01 = *reinterpret_cast<const float4*>(ftr + b01.y + ch0 + c4);
            const float4 c02 = *reinterpret_cast<const float4*>(ftr + b01.z + ch0 + c4);
            const float4 c03 = *reinterpret_cast<const float4*>(ftr + b01.w + ch0 + c4);
            const float4 c10 = *reinterpret_cast<const float4*>(ftr + b11.x + ch0 + c4);
            const float4 c11 = *reinterpret_cast<const float4*>(ftr + b11.y + ch0 + c4);
            const float4 c12 = *reinterpret_cast<const float4*>(ftr + b11.z + ch0 + c4);
            const float4 c13 = *reinterpret_cast<const float4*>(ftr + b11.w + ch0 + c4);

#define VAR_LANE(dd, W0, W1, V0a, V0b, V0c, V0d, V1a, V1b, V1c, V1d, CNT)                 \
            {                                                                              \
                {                                                                          \
                    const float a1 = W0.x * V0a.x + W0.y * V0b.x + W0.z * V0c.x + W0.w * V0d.x; \
                    const float a2 = W1.x * V1a.x + W1.y * V1b.x + W1.z * V1c.x + W1.w * V1d.x; \
                    s_tile[dd][c4 + 0][p] = var_one(fr.x, a1, a2, CNT);                    \
                }                                                                          \
                {                                                                          \
                    const float a1 = W0.x * V0a.y + W0.y * V0b.y + W0.z * V0c.y + W0.w * V0d.y; \
                    const float a2 = W1.x * V1a.y + W1.y * V1b.y + W1.z * V1c.y + W1.w * V1d.y; \
                    s_tile[dd][c4 + 1][p] = var_one(fr.y, a1, a2, CNT);                    \
                }                                                                          \
                {                                                                          \
                    const float a1 = W0.x * V0a.z + W0.y * V0b.z + W0.z * V0c.z + W0.w * V0d.z; \
                    const float a2 = W1.x * V1a.z + W1.y * V1b.z + W1.z * V1c.z + W1.w * V1d.z; \
                    s_tile[dd][c4 + 2][p] = var_one(fr.z, a1, a2, CNT);                    \
                }                                                                          \
                {                                                                          \
                    const float a1 = W0.x * V0a.w + W0.y * V0b.w + W0.z * V0c.w + W0.w * V0d.w; \
                    const float a2 = W1.x * V1a.w + W1.y * V1b.w + W1.z * V1c.w + W1.w * V1d.w; \
                    s_tile[dd][c4 + 3][p] = var_one(fr.w, a1, a2, CNT);                    \
                }                                                                          \
            }

            VAR_LANE(0, w00, w10, a00, a01, a02, a03, a10, a11, a12, a13, cnt0)
            VAR_LANE(1, w01, w11, c00, c01, c02, c03, c10, c11, c12, c13, cnt1)
#undef VAR_LANE
        }
        __syncthreads();

        // float4 stores: 2 depths x 32 channels x 24 quads = 1536 float4s
#pragma unroll
        for (int j = 0; j < (2 * (Cc / 2) * (Ww / 4)) / BDIM; ++j) {   // 6 iterations
            const int idx = tid + j * BDIM;
            const int dd  = idx / ((Cc / 2) * (Ww / 4));
            const int r   = idx - dd * ((Cc / 2) * (Ww / 4));
            const int cc  = r / (Ww / 4);
            const int pq  = r - cc * (Ww / 4);
            const float4 val = *reinterpret_cast<const float4*>(&s_tile[dd][cc][pq * 4]);
            *reinterpret_cast<float4*>(
                &out[(9 + ch0 + cc) * DHW + rowb0 + dd * HW + pq * 4]) = val;
        }
        __syncthreads();
    }
}

// ---------------------------------------------------------------------------
// fallback (no workspace needed) — only used if ws_size is too small
// ---------------------------------------------------------------------------
__global__ void __launch_bounds__(BDIM) ge_direct_kernel(
    const float* __restrict__ imgs, const float* __restrict__ feats,
    const float* __restrict__ proj, const float* __restrict__ depthv,
    float* __restrict__ out)
{
    const int idx = blockIdx.x * BDIM + threadIdx.x;
    if (idx >= NPIX) return;
    const int w = idx % Ww;
    const int t = idx / Ww;
    const int h = t % Hh;
    const int d = t / Hh;
    const int ohw = h * Ww + w;

    int offs[2][4];
    float wts[2][4];
    float msum;
    compute_warp(proj, depthv[d], (float)w, (float)h, offs, wts, msum);

    const int obase = d * HW + ohw;
#pragma unroll
    for (int c = 0; c < 3; ++c)
        out[c * DHW + obase] = imgs[c * HW + ohw];

#pragma unroll
    for (int v = 0; v < 2; ++v) {
        const float* ib = imgs + (size_t)(v + 1) * 3 * HW;
#pragma unroll
        for (int c = 0; c < 3; ++c) {
            const float* p = ib + (size_t)c * HW;
            const float acc = wts[v][0] * p[offs[v][0]] + wts[v][1] * p[offs[v][1]] +
                              wts[v][2] * p[offs[v][2]] + wts[v][3] * p[offs[v][3]];
            out[(3 * (v + 1) + c) * DHW + obase] = acc;
        }
    }

    const float count = 1.0f / msum;
    const float* f0 = feats;
    const float* f1 = feats + (size_t)Cc * HW;
    const float* f2 = feats + (size_t)2 * Cc * HW;
#pragma unroll 8
    for (int c = 0; c < Cc; ++c) {
        const float fr = f0[(size_t)c * HW + ohw];
        const float* p1 = f1 + (size_t)c * HW;
        const float* p2 = f2 + (size_t)c * HW;
        const float a1 = wts[0][0] * p1[offs[0][0]] + wts[0][1] * p1[offs[0][1]] +
                         wts[0][2] * p1[offs[0][2]] + wts[0][3] * p1[offs[0][3]];
        const float a2 = wts[1][0] * p2[offs[1][0]] + wts[1][1] * p2[offs[1][1]] +
                         wts[1][2] * p2[offs[1][2]] + wts[1][3] * p2[offs[1][3]];
        const float s = fr + a1 + a2;
        const float sq = fr * fr + a1 * a1 + a2 * a2;
        const float sc = s * count;
        out[(3 * Vv + c) * DHW + obase] = sq * count - sc * sc;
    }
}

extern "C" void kernel_launch(void* const* d_in, const int* in_sizes, int n_in,
                              void* d_out, int out_size, void* d_ws, size_t ws_size,
                              hipStream_t stream)
{
    const float* imgs   = (const float*)d_in[0];
    const float* feats  = (const float*)d_in[1];
    const float* proj   = (const float*)d_in[2];
    const float* depthv = (const float*)d_in[3];
    float* out = (float*)d_out;

    const size_t need = (size_t)Vv * HW * Cc * sizeof(float);   // 7.08 MB

    if (ws_size >= need) {
        float* ftr = (float*)d_ws;
        dim3 g1(HW / 64, Vv);
        transpose_feats_kernel<<<g1, BDIM, 0, stream>>>(feats, ftr);
        ge_row_kernel<<<Hh * (Dd / 2), BDIM, 0, stream>>>(imgs, ftr, proj, depthv, out);
    } else {
        const int blocks = (NPIX + BDIM - 1) / BDIM;
        ge_direct_kernel<<<blocks, BDIM, 0, stream>>>(imgs, feats, proj, depthv, out);
    }
}

// Round 7
// 168.710 us; speedup vs baseline: 1.1911x; 1.0082x over previous
//
#include <hip/hip_runtime.h>

#define BDIM 256

constexpr int Vv = 3, Cc = 64, Hh = 96, Ww = 96, Dd = 48;
constexpr int HW = Hh * Ww;          // 9216
constexpr int NPIX = Dd * HW;        // 442368
constexpr int DHW = Dd * HW;         // output channel stride
constexpr int NXCD = 8;
constexpr int WP = Ww + 4;           // 100: 16B-aligned s_tile rows for float4 stores

// ---------------------------------------------------------------------------
// Single-view warp computation (verified numerics: same fp contract(off)
// region and operation order as all passing rounds).
// ---------------------------------------------------------------------------
__device__ __forceinline__ void compute_warp_v(const float* __restrict__ P, float depth,
                                               float xf, float yf,
                                               int offs[4], float wts[4], float& inbf)
{
#pragma clang fp contract(off)
    const float r00 = P[0], r01 = P[1], r02 = P[2],  t0 = P[3];
    const float r10 = P[4], r11 = P[5], r12 = P[6],  t1 = P[7];
    const float r20 = P[8], r21 = P[9], r22 = P[10], t2 = P[11];

    const float px = ((r00 * xf + r01 * yf) + r02) + t0 / depth;
    const float py = ((r10 * xf + r11 * yf) + r12) + t1 / depth;
    const float pz = ((r20 * xf + r21 * yf) + r22) + t2 / depth;

    const float xy0 = px / pz;
    const float xy1 = py / pz;
    const float gx = xy0 / ((float)(Ww - 1) * 0.5f) - 1.0f;
    const float gy = xy1 / ((float)(Hh - 1) * 0.5f) - 1.0f;

    const bool inb = (gx > -1.0f) && (gx < 1.0f) && (gy > -1.0f) && (gy < 1.0f);
    inbf = inb ? 1.0f : 0.0f;

    const float sx = (gx + 1.0f) * 0.5f * (float)(Ww - 1);
    const float sy = (gy + 1.0f) * 0.5f * (float)(Hh - 1);
    const float x0 = floorf(sx), y0 = floorf(sy);
    const float wx1 = sx - x0, wy1 = sy - y0;
    const float wx0 = 1.0f - wx1, wy0 = 1.0f - wy1;

#pragma unroll
    for (int k = 0; k < 4; ++k) {
        const float xi = (k & 1) ? (x0 + 1.0f) : x0;
        const float yi = (k & 2) ? (y0 + 1.0f) : y0;
        const float wk = ((k & 1) ? wx1 : wx0) * ((k & 2) ? wy1 : wy0);
        const bool valid = (xi >= 0.0f) && (xi <= (float)(Ww - 1)) &&
                           (yi >= 0.0f) && (yi <= (float)(Hh - 1));
        const float xc = fminf(fmaxf(xi, 0.0f), (float)(Ww - 1));
        const float yc = fminf(fmaxf(yi, 0.0f), (float)(Hh - 1));
        offs[k] = (int)yc * Ww + (int)xc;
        wts[k] = valid ? wk : 0.0f;
    }
}

// 2-view wrapper for the fallback kernel.
__device__ __forceinline__ void compute_warp(const float* __restrict__ proj, float depth,
                                             float xf, float yf,
                                             int offs[2][4], float wts[2][4], float& msum)
{
    msum = 1.0f;
#pragma unroll
    for (int v = 0; v < 2; ++v) {
        float inb;
        compute_warp_v(proj + (v + 1) * 12, depth, xf, yf, offs[v], wts[v], inb);
        msum += inb;
    }
}

__device__ __forceinline__ float var_one(float fr, float a1, float a2, float cnt)
{
    const float s  = fr + a1 + a2;
    const float q  = fr * fr + a1 * a1 + a2 * a2;
    const float sc = s * cnt;
    return q * cnt - sc * sc;
}

// ---------------------------------------------------------------------------
// feats (V, C, HW) -> ftr (V, HW, C)   (channel-minor for coalesced reads)
// ---------------------------------------------------------------------------
__global__ void __launch_bounds__(BDIM) transpose_feats_kernel(const float* __restrict__ feats,
                                                               float* __restrict__ ft)
{
    __shared__ float tile[64][65];
    const int v  = blockIdx.y;
    const int p0 = blockIdx.x * 64;
    const float* src = feats + (size_t)v * Cc * HW;

    const int px = threadIdx.x & 63;
    const int c0 = threadIdx.x >> 6;
#pragma unroll
    for (int c = c0; c < Cc; c += 4)
        tile[c][px] = src[(size_t)c * HW + p0 + px];
    __syncthreads();

    const int cc  = threadIdx.x & 63;
    const int pr0 = threadIdx.x >> 6;
    float* dst = ft + ((size_t)v * HW + p0) * Cc;
#pragma unroll
    for (int p = pr0; p < 64; p += 4)
        dst[p * Cc + cc] = tile[cc][p];
}

// ---------------------------------------------------------------------------
// main kernel: one block per (h, depth-pair) — R6 structure (measured best:
// interleaved depth-pair gathers, XCD-chunked blocks, float4 tile stores),
// with R7's occupancy fix: single-depth s_tile slab (12.8 KB instead of
// 25.6 KB) -- dd=1 results held in 12 registers (statically indexed) and
// flushed through the same slab after dd=0's store. LDS 39.4 -> 26.6 KB:
// 4 -> 6 blocks/CU, 16 -> 24 waves/CU on a latency-bound kernel.
// ---------------------------------------------------------------------------
__global__ void __launch_bounds__(BDIM, 6) ge_row_kernel(
    const float* __restrict__ imgs, const float* __restrict__ ftr,
    const float* __restrict__ proj, const float* __restrict__ depthv,
    float* __restrict__ out)
{
    __shared__ alignas(16) float s_tile[Cc / 2][WP];    // 32ch x 100 = 12.8 KB
    __shared__ alignas(16) int   s_base[2][2][Ww][4];   // [view][dd][pixel][corner]
    __shared__ alignas(16) float s_wt[2][2][Ww][4];
    __shared__ float s_inb[2][2][Ww];

    // XCD-chunked bijective swizzle: phys blockIdx round-robins XCDs (%8);
    // logical blk ordered (h-major, depth-pair-minor). 2304 % 8 == 0.
    const int nper = (Hh * (Dd / 2)) / NXCD;            // 288
    const int blk  = (blockIdx.x & (NXCD - 1)) * nper + (blockIdx.x >> 3);
    const int h   = blk / (Dd / 2);
    const int dq  = blk - h * (Dd / 2);
    const int d0  = dq * 2;
    const int tid = threadIdx.x;
    const int rowb0 = d0 * HW + h * Ww;      // output offset of (d0,h,0)

    // ---- Phase 1: tid<192 one (view,pixel) each (both depths);
    //      tid>=192 (previously idle wave) does the ref-image copy ----
    if (tid < 2 * Ww) {
        const int v = (tid >= Ww) ? 1 : 0;
        const int w = tid - v * Ww;
        const float* ib = imgs + (size_t)(v + 1) * 3 * HW;
#pragma unroll
        for (int dd = 0; dd < 2; ++dd) {
            int offs[4];
            float wts[4];
            float inb;
            compute_warp_v(proj + (v + 1) * 12, depthv[d0 + dd], (float)w, (float)h,
                           offs, wts, inb);
            s_inb[v][dd][w] = inb;
#pragma unroll
            for (int k = 0; k < 4; ++k) {
                s_base[v][dd][w][k] = ((v + 1) * HW + offs[k]) * Cc;
                s_wt[v][dd][w][k]   = wts[k];
            }
            // warped image channels for this view/depth
#pragma unroll
            for (int c = 0; c < 3; ++c) {
                const float* p = ib + (size_t)c * HW;
                const float acc = wts[0] * p[offs[0]] + wts[1] * p[offs[1]] +
                                  wts[2] * p[offs[2]] + wts[3] * p[offs[3]];
                out[(3 * (v + 1) + c) * DHW + rowb0 + dd * HW + w] = acc;
            }
        }
    } else {
        for (int w = tid - 2 * Ww; w < Ww; w += BDIM - 2 * Ww) {
            const int hw = h * Ww + w;
#pragma unroll
            for (int c = 0; c < 3; ++c) {
                const float val = imgs[c * HW + hw];
                out[c * DHW + rowb0 + w]      = val;   // depth d0
                out[c * DHW + rowb0 + HW + w] = val;   // depth d0+1
            }
        }
    }
    __syncthreads();

    // ---- Phase 2/3: two channel-halves; both depths gathered interleaved,
    //      dd=0 -> s_tile, dd=1 -> registers, flushed through the slab ----
    const int wave = tid >> 6;
    const int lane = tid & 63;
    const int sub  = lane >> 3;          // pixel-within-octet 0..7
    const int cq   = lane & 7;           // channel quad within half
    const int c4   = cq << 2;            // 0,4,...,28
    const int p0   = wave * (Ww / 4);    // 24 pixels per wave

#pragma unroll
    for (int hc = 0; hc < 2; ++hc) {
        const int ch0 = hc * (Cc / 2);
        float4 keep[3];                  // dd=1 results, statically indexed

#pragma unroll
        for (int i = 0; i < 3; ++i) {    // 3 iterations x 8 pixels
            const int p = p0 + i * 8 + sub;
            const int4   b00 = *reinterpret_cast<const int4*>(&s_base[0][0][p][0]);
            const int4   b10 = *reinterpret_cast<const int4*>(&s_base[1][0][p][0]);
            const int4   b01 = *reinterpret_cast<const int4*>(&s_base[0][1][p][0]);
            const int4   b11 = *reinterpret_cast<const int4*>(&s_base[1][1][p][0]);
            const float4 w00 = *reinterpret_cast<const float4*>(&s_wt[0][0][p][0]);
            const float4 w10 = *reinterpret_cast<const float4*>(&s_wt[1][0][p][0]);
            const float4 w01 = *reinterpret_cast<const float4*>(&s_wt[0][1][p][0]);
            const float4 w11 = *reinterpret_cast<const float4*>(&s_wt[1][1][p][0]);
            const float cnt0 = 1.0f / (1.0f + s_inb[0][0][p] + s_inb[1][0][p]);
            const float cnt1 = 1.0f / (1.0f + s_inb[0][1][p] + s_inb[1][1][p]);

            // depth-invariant ref feature: loaded once, reused for both depths
            const float4 fr = *reinterpret_cast<const float4*>(
                ftr + (size_t)(h * Ww + p) * Cc + ch0 + c4);

            // depth d0 corners
            const float4 a00 = *reinterpret_cast<const float4*>(ftr + b00.x + ch0 + c4);
            const float4 a01 = *reinterpret_cast<const float4*>(ftr + b00.y + ch0 + c4);
            const float4 a02 = *reinterpret_cast<const float4*>(ftr + b00.z + ch0 + c4);
            const float4 a03 = *reinterpret_cast<const float4*>(ftr + b00.w + ch0 + c4);
            const float4 a10 = *reinterpret_cast<const float4*>(ftr + b10.x + ch0 + c4);
            const float4 a11 = *reinterpret_cast<const float4*>(ftr + b10.y + ch0 + c4);
            const float4 a12 = *reinterpret_cast<const float4*>(ftr + b10.z + ch0 + c4);
            const float4 a13 = *reinterpret_cast<const float4*>(ftr + b10.w + ch0 + c4);
            // depth d0+1 corners (mostly the same 128B lines -> L1 hits)
            const float4 c00 = *reinterpret_cast<const float4*>(ftr + b01.x + ch0 + c4);
            const float4 c01 = *reinterpret_cast<const float4*>(ftr + b01.y + ch0 + c4);
            const float4 c02 = *reinterpret_cast<const float4*>(ftr + b01.z + ch0 + c4);
            const float4 c03 = *reinterpret_cast<const float4*>(ftr + b01.w + ch0 + c4);
            const float4 c10 = *reinterpret_cast<const float4*>(ftr + b11.x + ch0 + c4);
            const float4 c11 = *reinterpret_cast<const float4*>(ftr + b11.y + ch0 + c4);
            const float4 c12 = *reinterpret_cast<const float4*>(ftr + b11.z + ch0 + c4);
            const float4 c13 = *reinterpret_cast<const float4*>(ftr + b11.w + ch0 + c4);

            // dd = 0 -> s_tile
            {
                const float a1 = w00.x * a00.x + w00.y * a01.x + w00.z * a02.x + w00.w * a03.x;
                const float a2 = w10.x * a10.x + w10.y * a11.x + w10.z * a12.x + w10.w * a13.x;
                s_tile[c4 + 0][p] = var_one(fr.x, a1, a2, cnt0);
            }
            {
                const float a1 = w00.x * a00.y + w00.y * a01.y + w00.z * a02.y + w00.w * a03.y;
                const float a2 = w10.x * a10.y + w10.y * a11.y + w10.z * a12.y + w10.w * a13.y;
                s_tile[c4 + 1][p] = var_one(fr.y, a1, a2, cnt0);
            }
            {
                const float a1 = w00.x * a00.z + w00.y * a01.z + w00.z * a02.z + w00.w * a03.z;
                const float a2 = w10.x * a10.z + w10.y * a11.z + w10.z * a12.z + w10.w * a13.z;
                s_tile[c4 + 2][p] = var_one(fr.z, a1, a2, cnt0);
            }
            {
                const float a1 = w00.x * a00.w + w00.y * a01.w + w00.z * a02.w + w00.w * a03.w;
                const float a2 = w10.x * a10.w + w10.y * a11.w + w10.z * a12.w + w10.w * a13.w;
                s_tile[c4 + 3][p] = var_one(fr.w, a1, a2, cnt0);
            }
            // dd = 1 -> registers
            float4 kv;
            {
                const float a1 = w01.x * c00.x + w01.y * c01.x + w01.z * c02.x + w01.w * c03.x;
                const float a2 = w11.x * c10.x + w11.y * c11.x + w11.z * c12.x + w11.w * c13.x;
                kv.x = var_one(fr.x, a1, a2, cnt1);
            }
            {
                const float a1 = w01.x * c00.y + w01.y * c01.y + w01.z * c02.y + w01.w * c03.y;
                const float a2 = w11.x * c10.y + w11.y * c11.y + w11.z * c12.y + w11.w * c13.y;
                kv.y = var_one(fr.y, a1, a2, cnt1);
            }
            {
                const float a1 = w01.x * c00.z + w01.y * c01.z + w01.z * c02.z + w01.w * c03.z;
                const float a2 = w11.x * c10.z + w11.y * c11.z + w11.z * c12.z + w11.w * c13.z;
                kv.z = var_one(fr.z, a1, a2, cnt1);
            }
            {
                const float a1 = w01.x * c00.w + w01.y * c01.w + w01.z * c02.w + w01.w * c03.w;
                const float a2 = w11.x * c10.w + w11.y * c11.w + w11.z * c12.w + w11.w * c13.w;
                kv.w = var_one(fr.w, a1, a2, cnt1);
            }
            keep[i] = kv;
        }
        __syncthreads();

        // store dd=0 slab: 32ch x 24 quads = 768 float4s, 3 iterations
#pragma unroll
        for (int j = 0; j < ((Cc / 2) * (Ww / 4)) / BDIM; ++j) {
            const int idx = tid + j * BDIM;
            const int cc  = idx / (Ww / 4);
            const int pq  = idx - cc * (Ww / 4);
            const float4 val = *reinterpret_cast<const float4*>(&s_tile[cc][pq * 4]);
            *reinterpret_cast<float4*>(
                &out[(9 + ch0 + cc) * DHW + rowb0 + pq * 4]) = val;
        }
        __syncthreads();

        // flush dd=1 registers through the same slab
#pragma unroll
        for (int i = 0; i < 3; ++i) {
            const int p = p0 + i * 8 + sub;
            s_tile[c4 + 0][p] = keep[i].x;
            s_tile[c4 + 1][p] = keep[i].y;
            s_tile[c4 + 2][p] = keep[i].z;
            s_tile[c4 + 3][p] = keep[i].w;
        }
        __syncthreads();

        // store dd=1 slab
#pragma unroll
        for (int j = 0; j < ((Cc / 2) * (Ww / 4)) / BDIM; ++j) {
            const int idx = tid + j * BDIM;
            const int cc  = idx / (Ww / 4);
            const int pq  = idx - cc * (Ww / 4);
            const float4 val = *reinterpret_cast<const float4*>(&s_tile[cc][pq * 4]);
            *reinterpret_cast<float4*>(
                &out[(9 + ch0 + cc) * DHW + rowb0 + HW + pq * 4]) = val;
        }
        if (hc == 0) __syncthreads();
    }
}

// ---------------------------------------------------------------------------
// fallback (no workspace needed) — only used if ws_size is too small
// ---------------------------------------------------------------------------
__global__ void __launch_bounds__(BDIM) ge_direct_kernel(
    const float* __restrict__ imgs, const float* __restrict__ feats,
    const float* __restrict__ proj, const float* __restrict__ depthv,
    float* __restrict__ out)
{
    const int idx = blockIdx.x * BDIM + threadIdx.x;
    if (idx >= NPIX) return;
    const int w = idx % Ww;
    const int t = idx / Ww;
    const int h = t % Hh;
    const int d = t / Hh;
    const int ohw = h * Ww + w;

    int offs[2][4];
    float wts[2][4];
    float msum;
    compute_warp(proj, depthv[d], (float)w, (float)h, offs, wts, msum);

    const int obase = d * HW + ohw;
#pragma unroll
    for (int c = 0; c < 3; ++c)
        out[c * DHW + obase] = imgs[c * HW + ohw];

#pragma unroll
    for (int v = 0; v < 2; ++v) {
        const float* ib = imgs + (size_t)(v + 1) * 3 * HW;
#pragma unroll
        for (int c = 0; c < 3; ++c) {
            const float* p = ib + (size_t)c * HW;
            const float acc = wts[v][0] * p[offs[v][0]] + wts[v][1] * p[offs[v][1]] +
                              wts[v][2] * p[offs[v][2]] + wts[v][3] * p[offs[v][3]];
            out[(3 * (v + 1) + c) * DHW + obase] = acc;
        }
    }

    const float count = 1.0f / msum;
    const float* f0 = feats;
    const float* f1 = feats + (size_t)Cc * HW;
    const float* f2 = feats + (size_t)2 * Cc * HW;
#pragma unroll 8
    for (int c = 0; c < Cc; ++c) {
        const float fr = f0[(size_t)c * HW + ohw];
        const float* p1 = f1 + (size_t)c * HW;
        const float* p2 = f2 + (size_t)c * HW;
        const float a1 = wts[0][0] * p1[offs[0][0]] + wts[0][1] * p1[offs[0][1]] +
                         wts[0][2] * p1[offs[0][2]] + wts[0][3] * p1[offs[0][3]];
        const float a2 = wts[1][0] * p2[offs[1][0]] + wts[1][1] * p2[offs[1][1]] +
                         wts[1][2] * p2[offs[1][2]] + wts[1][3] * p2[offs[1][3]];
        const float s = fr + a1 + a2;
        const float sq = fr * fr + a1 * a1 + a2 * a2;
        const float sc = s * count;
        out[(3 * Vv + c) * DHW + obase] = sq * count - sc * sc;
    }
}

extern "C" void kernel_launch(void* const* d_in, const int* in_sizes, int n_in,
                              void* d_out, int out_size, void* d_ws, size_t ws_size,
                              hipStream_t stream)
{
    const float* imgs   = (const float*)d_in[0];
    const float* feats  = (const float*)d_in[1];
    const float* proj   = (const float*)d_in[2];
    const float* depthv = (const float*)d_in[3];
    float* out = (float*)d_out;

    const size_t need = (size_t)Vv * HW * Cc * sizeof(float);   // 7.08 MB

    if (ws_size >= need) {
        float* ftr = (float*)d_ws;
        dim3 g1(HW / 64, Vv);
        transpose_feats_kernel<<<g1, BDIM, 0, stream>>>(feats, ftr);
        ge_row_kernel<<<Hh * (Dd / 2), BDIM, 0, stream>>>(imgs, ftr, proj, depthv, out);
    } else {
        const int blocks = (NPIX + BDIM - 1) / BDIM;
        ge_direct_kernel<<<blocks, BDIM, 0, stream>>>(imgs, feats, proj, depthv, out);
    }
}